// Round 8
// baseline (263.041 us; speedup 1.0000x reference)
//
#include <hip/hip_runtime.h>

#define N_NODES 100000
#define E_EDGES 1600000

// bucketed CSR build
#define BSHIFT 7
#define BSIZE 128
#define NBUCK ((N_NODES + BSIZE - 1) / BSIZE)           // 782
#define STAGE_TPB 1024
#define STAGE_EPT 16
#define STAGE_CHUNK (STAGE_TPB * STAGE_EPT)             // 16384
#define NREP 4                                           // LDS table replicas in stage
#define BUCKET_CAP 4096                                  // staged slots per bucket (mean 2046)

typedef __attribute__((ext_vector_type(8))) short short8;
typedef __attribute__((ext_vector_type(4))) float float4v;

// ---- bf16 helpers (RNE) ----
__device__ inline unsigned short f2bf(float f) {
    union { float f; unsigned u; } t; t.f = f;
    unsigned r = (t.u + 0x7fffu + ((t.u >> 16) & 1u)) >> 16;
    return (unsigned short)r;
}
__device__ inline float bf2f(unsigned short h) {
    union { unsigned u; float f; } t; t.u = ((unsigned)h) << 16; return t.f;
}
__device__ inline unsigned pack_bf16x2(float a, float b) {
    return (unsigned)f2bf(a) | ((unsigned)f2bf(b) << 16);
}
__device__ inline float bf_lo(unsigned u) { union { unsigned u; float f; } t; t.u = u << 16; return t.f; }
__device__ inline float bf_hi(unsigned u) { union { unsigned u; float f; } t; t.u = u & 0xffff0000u; return t.f; }

// ---------------- cursor init: gcursor[b] = b * BUCKET_CAP ----------------
__global__ void cursor_init_kernel(int* __restrict__ gcursor) {
    int b = blockIdx.x * blockDim.x + threadIdx.x;
    if (b < NBUCK) gcursor[b] = b * BUCKET_CAP;
}

// ---------------- stage edges into fixed-capacity bucket regions ----------------
// record = src | ((dst & 127) << 17); src < 2^17
// 4x replicated LDS tables (one per 256-thread slice) to cut same-address atomic serialization.
__global__ void __launch_bounds__(STAGE_TPB) stage_kernel(
    const int* __restrict__ src, const int* __restrict__ dst,
    int* __restrict__ gcursor, unsigned* __restrict__ staged, int E) {
    __shared__ int hist[NREP][NBUCK];
    __shared__ int base[NREP][NBUCK];   // doubles as the per-replica write cursor
    const int tid = threadIdx.x;
    const int rep = (tid >> 8) & (NREP - 1);
    const int e0 = blockIdx.x * STAGE_CHUNK;
    for (int i = tid; i < NREP * NBUCK; i += STAGE_TPB) ((int*)hist)[i] = 0;
    __syncthreads();
    int d[STAGE_EPT], s[STAGE_EPT];
#pragma unroll
    for (int k = 0; k < STAGE_EPT; ++k) {
        int e = e0 + k * STAGE_TPB + tid;
        if (e < E) {
            d[k] = dst[e];
            s[k] = src[e];
            atomicAdd(&hist[rep][d[k] >> BSHIFT], 1);
        } else {
            d[k] = -1;
        }
    }
    __syncthreads();
    for (int i = tid; i < NBUCK; i += STAGE_TPB) {
        int h0 = hist[0][i], h1 = hist[1][i], h2 = hist[2][i], h3 = hist[3][i];
        int t = h0 + h1 + h2 + h3;
        if (t > 0) {
            int g = atomicAdd(&gcursor[i], t);
            base[0][i] = g;
            base[1][i] = g + h0;
            base[2][i] = g + h0 + h1;
            base[3][i] = g + h0 + h1 + h2;
        }
    }
    __syncthreads();
#pragma unroll
    for (int k = 0; k < STAGE_EPT; ++k) {
        if (d[k] >= 0) {
            int b = d[k] >> BSHIFT;
            int pos = atomicAdd(&base[rep][b], 1);
            if (pos < (b + 1) * BUCKET_CAP)  // statistically never false; memory-safety clamp
                staged[pos] = (unsigned)s[k] | ((unsigned)(d[k] & (BSIZE - 1)) << 17);
        }
    }
}

// ---------------- post-stage scan: counts from cursors -> boff ----------------
__global__ void bscan_kernel(const int* __restrict__ gcursor, int* __restrict__ boff) {
    __shared__ int s[1024];
    const int tid = threadIdx.x;
    int v = 0;
    if (tid < NBUCK) {
        v = gcursor[tid] - tid * BUCKET_CAP;   // bucket count
        if (v > BUCKET_CAP) v = BUCKET_CAP;
    }
    s[tid] = v;
    __syncthreads();
    for (int off = 1; off < 1024; off <<= 1) {
        int t = (tid >= off) ? s[tid - off] : 0;
        __syncthreads();
        s[tid] += t;
        __syncthreads();
    }
    if (tid < NBUCK) boff[tid] = s[tid] - v;  // exclusive
    if (tid == NBUCK - 1) boff[NBUCK] = s[tid];
}

// ---------------- per-bucket: deg/dinv/rowptr + fine CSR, all coalesced ----------------
__global__ void bucket_csr_kernel(const unsigned* __restrict__ staged,
                                  const int* __restrict__ boff,
                                  int* __restrict__ deg, float* __restrict__ dinv,
                                  int* __restrict__ rowptr, int* __restrict__ csrc, int n) {
    __shared__ int ldeg[BSIZE];
    __shared__ int lrp[BSIZE];
    __shared__ int lcnt[BSIZE];
    __shared__ unsigned lrec[BUCKET_CAP];
    __shared__ int lsrc[BUCKET_CAP];
    const int b = blockIdx.x;
    const int node0 = b * BSIZE;
    const int nn = min(BSIZE, n - node0);
    const int tid = threadIdx.x;  // 256
    if (tid < BSIZE) { ldeg[tid] = 0; lcnt[tid] = 0; }
    __syncthreads();
    const int ebase = boff[b];
    const int ecnt = min(boff[b + 1] - ebase, BUCKET_CAP);
    const int sbase = b * BUCKET_CAP;
    for (int i = tid; i < ecnt; i += 256) {
        unsigned r = staged[sbase + i];
        lrec[i] = r;
        atomicAdd(&ldeg[r >> 17], 1);
    }
    __syncthreads();
    int mydeg = (tid < BSIZE) ? ldeg[tid] : 0;
    if (tid < BSIZE) lrp[tid] = mydeg;
    __syncthreads();
    for (int off = 1; off < BSIZE; off <<= 1) {
        int v = 0;
        if (tid < BSIZE && tid >= off) v = lrp[tid - off];
        __syncthreads();
        if (tid < BSIZE) lrp[tid] += v;
        __syncthreads();
    }
    if (tid < BSIZE) {
        int ex = lrp[tid] - mydeg;  // exclusive
        lrp[tid] = ex;
        if (tid < nn) {
            deg[node0 + tid] = mydeg;
            dinv[node0 + tid] = rsqrtf((float)mydeg + 2.0f);
            rowptr[node0 + tid] = ebase + ex;
        }
    }
    __syncthreads();
    for (int i = tid; i < ecnt; i += 256) {
        unsigned r = lrec[i];
        int dl = (int)(r >> 17);
        int sv = (int)(r & 0x1FFFFu);
        int pos = lrp[dl] + atomicAdd(&lcnt[dl], 1);
        if (pos < BUCKET_CAP) lsrc[pos] = sv;
    }
    __syncthreads();
    for (int i = tid; i < ecnt; i += 256)
        csrc[ebase + i] = lsrc[i];
}

// ---------------- MFMA linear: HS = bf16x2((X@W)*dinv), chunked + (f,f+16) pairing ----------------
// Split GEMM: Ahi*Whi + Alo*Whi + Ahi*Wlo gives ~fp32 accuracy with bf16 MFMA.
// C/D layout (16x16x32_bf16): col=lane&15, row=(lane>>4)*4+reg.  A: [m=lane&15][k=(lane>>4)*8+j].
// HS chunk ch holds features [32ch,32ch+32); uint c of a row packs (feat 32ch+c, feat 32ch+16+c).
template <int FOUT>   // 64 or 32
__global__ void __launch_bounds__(256) linear_mfma_kernel(
    const float* __restrict__ X, const float* __restrict__ W,
    const float* __restrict__ dinv, unsigned* __restrict__ HS, int n) {
    constexpr int NT = FOUT / 16;            // n-tiles
    const int NTILES_M = n / 16;             // 6250 (n divisible by 16)
    const int lane = threadIdx.x & 63;
    const int gwave = blockIdx.x * 4 + (threadIdx.x >> 6);
    const int nwaves = gridDim.x * 4;
    const int m = lane & 15;
    const int q = lane >> 4;  // 0..3

    // W fragments in registers (hi+lo), loaded once per wave
    short8 Bhi[2][NT], Blo[2][NT];
#pragma unroll
    for (int ks = 0; ks < 2; ++ks)
#pragma unroll
        for (int nt = 0; nt < NT; ++nt) {
            short8 bh, bl;
#pragma unroll
            for (int j = 0; j < 8; ++j) {
                int k = ks * 32 + q * 8 + j;
                float wv = W[k * FOUT + nt * 16 + m];
                unsigned short h = f2bf(wv);
                bh[j] = (short)h;
                bl[j] = (short)f2bf(wv - bf2f(h));
            }
            Bhi[ks][nt] = bh;
            Blo[ks][nt] = bl;
        }

    for (int tile = gwave; tile < NTILES_M; tile += nwaves) {
        const int row0 = tile * 16;
        float4v C[NT];
#pragma unroll
        for (int nt = 0; nt < NT; ++nt) C[nt] = (float4v){0.f, 0.f, 0.f, 0.f};
#pragma unroll
        for (int ks = 0; ks < 2; ++ks) {
            const float* xp = X + (size_t)(row0 + m) * 64 + ks * 32 + q * 8;
            float4v x0 = *(const float4v*)xp;
            float4v x1 = *(const float4v*)(xp + 4);
            short8 Ahi, Alo;
#pragma unroll
            for (int j = 0; j < 4; ++j) {
                unsigned short h0 = f2bf(x0[j]);
                Ahi[j] = (short)h0;
                Alo[j] = (short)f2bf(x0[j] - bf2f(h0));
                unsigned short h1 = f2bf(x1[j]);
                Ahi[4 + j] = (short)h1;
                Alo[4 + j] = (short)f2bf(x1[j] - bf2f(h1));
            }
#pragma unroll
            for (int nt = 0; nt < NT; ++nt) {
                C[nt] = __builtin_amdgcn_mfma_f32_16x16x32_bf16(Ahi, Bhi[ks][nt], C[nt], 0, 0, 0);
                C[nt] = __builtin_amdgcn_mfma_f32_16x16x32_bf16(Alo, Bhi[ks][nt], C[nt], 0, 0, 0);
                C[nt] = __builtin_amdgcn_mfma_f32_16x16x32_bf16(Ahi, Blo[ks][nt], C[nt], 0, 0, 0);
            }
        }
        // epilogue: pair n-tile 2ch (cols 0-15) with 2ch+1 (cols 16-31) of chunk ch
#pragma unroll
        for (int ch = 0; ch < NT / 2; ++ch) {
#pragma unroll
            for (int reg = 0; reg < 4; ++reg) {
                int r = row0 + q * 4 + reg;
                float di = dinv[r];
                unsigned u = pack_bf16x2(C[2 * ch][reg] * di, C[2 * ch + 1][reg] * di);
                HS[(size_t)ch * n * 16 + (size_t)r * 16 + m] = u;
            }
        }
    }
}

// ---------------- fused gather over one 32-feature chunk ----------------
// G=16 lanes/node; uint l of a row = (feat base+l, feat base+16+l).
// Edge batching: one coalesced csrc load per 16 edges, broadcast via shfl ->
// 16 independent HS loads in flight per group (latency hiding).
template <bool RELU>
__global__ void gather_chunk_kernel(const int* __restrict__ rowptr, const int* __restrict__ deg,
                                    const int* __restrict__ csrc, const unsigned* __restrict__ HS,
                                    const float* __restrict__ dinv, const float* __restrict__ bias0,
                                    float* __restrict__ OUT, int out_stride, int out_off,
                                    int n) {
    constexpr int G = 16;
    constexpr int NPB = 256 / G;  // 16 nodes per block
    int node = blockIdx.x * NPB + (threadIdx.x / G);
    int l = threadIdx.x % G;
    if (node >= n) return;
    int start = rowptr[node];
    int cnt = deg[node];
    unsigned us = HS[(size_t)node * G + l];
    float a0 = 2.0f * bf_lo(us);
    float a1 = 2.0f * bf_hi(us);
    int end = start + cnt;
    for (int jb = start; jb < end; jb += G) {
        int mye = jb + l;
        int msrc = (mye < end) ? csrc[mye] : -1;
#pragma unroll
        for (int k = 0; k < G; ++k) {
            int s = __shfl(msrc, k, G);   // group-uniform
            if (s >= 0) {
                unsigned u = HS[(size_t)s * G + l];
                a0 += bf_lo(u);
                a1 += bf_hi(u);
            }
        }
    }
    float dd = dinv[node];
    float o0 = a0 * dd + bias0[l];
    float o1 = a1 * dd + bias0[16 + l];
    if (RELU) { o0 = fmaxf(o0, 0.0f); o1 = fmaxf(o1, 0.0f); }
    OUT[(size_t)node * out_stride + out_off + l] = o0;
    OUT[(size_t)node * out_stride + out_off + 16 + l] = o1;
}

extern "C" void kernel_launch(void* const* d_in, const int* in_sizes, int n_in,
                              void* d_out, int out_size, void* d_ws, size_t ws_size,
                              hipStream_t stream) {
    const float* x  = (const float*)d_in[0];   // [N,64]
    const int*   ei = (const int*)d_in[1];     // [2,E] row-major: src then dst
    const float* W1 = (const float*)d_in[2];   // [64,64]
    const float* b1 = (const float*)d_in[3];   // [64]
    const float* W2 = (const float*)d_in[4];   // [64,32]
    const float* b2 = (const float*)d_in[5];   // [32]

    const int* srcp = ei;
    const int* dstp = ei + E_EDGES;

    // tuple return order: (out [N,32], feature_map [N,64]) concatenated flat
    float* out = (float*)d_out;                   // N*32
    float* fm  = (float*)d_out + N_NODES * 32;    // N*64 (also h1 input to layer 2)

    // workspace layout
    char* w = (char*)d_ws;
    int*      gcursor = (int*)w;       w += sizeof(int) * NBUCK;
    int*      boff    = (int*)w;       w += sizeof(int) * (NBUCK + 1);
    int*      deg     = (int*)w;       w += sizeof(int) * N_NODES;
    int*      rowptr  = (int*)w;       w += sizeof(int) * N_NODES;
    float*    dinv    = (float*)w;     w += sizeof(float) * N_NODES;
    int*      csrc    = (int*)w;       w += sizeof(int) * E_EDGES;
    unsigned* staged  = (unsigned*)w;  w += sizeof(unsigned) * (size_t)NBUCK * BUCKET_CAP;
    unsigned* HS1     = (unsigned*)w;  w += sizeof(unsigned) * (size_t)N_NODES * 32;  // 2 chunks x N x 16
    unsigned* HS2     = (unsigned*)w;  w += sizeof(unsigned) * (size_t)N_NODES * 16;  // 1 chunk

    // ---- graph preprocessing (shared by both layers) ----
    cursor_init_kernel<<<(NBUCK + 255) / 256, 256, 0, stream>>>(gcursor);
    stage_kernel<<<(E_EDGES + STAGE_CHUNK - 1) / STAGE_CHUNK, STAGE_TPB, 0, stream>>>(
        srcp, dstp, gcursor, staged, E_EDGES);
    bscan_kernel<<<1, 1024, 0, stream>>>(gcursor, boff);
    bucket_csr_kernel<<<NBUCK, 256, 0, stream>>>(staged, boff, deg, dinv, rowptr, csrc, N_NODES);

    // ---- layer 1: HS1 = bf16((x@W1)*dinv) via MFMA; fm = relu(gather) per chunk ----
    linear_mfma_kernel<64><<<512, 256, 0, stream>>>(x, W1, dinv, HS1, N_NODES);
    gather_chunk_kernel<true><<<(N_NODES + 15) / 16, 256, 0, stream>>>(
        rowptr, deg, csrc, HS1, dinv, b1, fm, 64, 0, N_NODES);
    gather_chunk_kernel<true><<<(N_NODES + 15) / 16, 256, 0, stream>>>(
        rowptr, deg, csrc, HS1 + (size_t)N_NODES * 16, dinv, b1 + 32, fm, 64, 32, N_NODES);

    // ---- layer 2: HS2 = bf16((fm@W2)*dinv) via MFMA; out = gather (one chunk) ----
    linear_mfma_kernel<32><<<512, 256, 0, stream>>>(fm, W2, dinv, HS2, N_NODES);
    gather_chunk_kernel<false><<<(N_NODES + 15) / 16, 256, 0, stream>>>(
        rowptr, deg, csrc, HS2, dinv, b2, out, 32, 0, N_NODES);
}

// Round 9
// 225.060 us; speedup vs baseline: 1.1688x; 1.1688x over previous
//
#include <hip/hip_runtime.h>

#define N_NODES 100000
#define E_EDGES 1600000

// bucketed CSR build
#define BSHIFT 7
#define BSIZE 128
#define NBUCK ((N_NODES + BSIZE - 1) / BSIZE)           // 782
#define STAGE_TPB 1024
#define STAGE_EPT 16
#define STAGE_CHUNK (STAGE_TPB * STAGE_EPT)             // 16384
#define NREP 4                                           // LDS table replicas in stage
#define BUCKET_CAP 4096                                  // staged slots per bucket (mean 2046)

typedef __attribute__((ext_vector_type(8))) short short8;
typedef __attribute__((ext_vector_type(4))) float float4v;

// ---- bf16 helpers (RNE) ----
__device__ inline unsigned short f2bf(float f) {
    union { float f; unsigned u; } t; t.f = f;
    unsigned r = (t.u + 0x7fffu + ((t.u >> 16) & 1u)) >> 16;
    return (unsigned short)r;
}
__device__ inline float bf2f(unsigned short h) {
    union { unsigned u; float f; } t; t.u = ((unsigned)h) << 16; return t.f;
}
__device__ inline unsigned pack_bf16x2(float a, float b) {
    return (unsigned)f2bf(a) | ((unsigned)f2bf(b) << 16);
}
__device__ inline float bf_lo(unsigned u) { union { unsigned u; float f; } t; t.u = u << 16; return t.f; }
__device__ inline float bf_hi(unsigned u) { union { unsigned u; float f; } t; t.u = u & 0xffff0000u; return t.f; }

// ---------------- cursor init: gcursor[b] = b * BUCKET_CAP ----------------
__global__ void cursor_init_kernel(int* __restrict__ gcursor) {
    int b = blockIdx.x * blockDim.x + threadIdx.x;
    if (b < NBUCK) gcursor[b] = b * BUCKET_CAP;
}

// ---------------- stage edges into fixed-capacity bucket regions ----------------
// record = src | ((dst & 127) << 17); src < 2^17
// 4x replicated LDS tables (one per 256-thread slice) to cut same-address atomic serialization.
__global__ void __launch_bounds__(STAGE_TPB) stage_kernel(
    const int* __restrict__ src, const int* __restrict__ dst,
    int* __restrict__ gcursor, unsigned* __restrict__ staged, int E) {
    __shared__ int hist[NREP][NBUCK];
    __shared__ int base[NREP][NBUCK];   // doubles as the per-replica write cursor
    const int tid = threadIdx.x;
    const int rep = (tid >> 8) & (NREP - 1);
    const int e0 = blockIdx.x * STAGE_CHUNK;
    for (int i = tid; i < NREP * NBUCK; i += STAGE_TPB) ((int*)hist)[i] = 0;
    __syncthreads();
    int d[STAGE_EPT], s[STAGE_EPT];
#pragma unroll
    for (int k = 0; k < STAGE_EPT; ++k) {
        int e = e0 + k * STAGE_TPB + tid;
        if (e < E) {
            d[k] = dst[e];
            s[k] = src[e];
            atomicAdd(&hist[rep][d[k] >> BSHIFT], 1);
        } else {
            d[k] = -1;
        }
    }
    __syncthreads();
    for (int i = tid; i < NBUCK; i += STAGE_TPB) {
        int h0 = hist[0][i], h1 = hist[1][i], h2 = hist[2][i], h3 = hist[3][i];
        int t = h0 + h1 + h2 + h3;
        if (t > 0) {
            int g = atomicAdd(&gcursor[i], t);
            base[0][i] = g;
            base[1][i] = g + h0;
            base[2][i] = g + h0 + h1;
            base[3][i] = g + h0 + h1 + h2;
        }
    }
    __syncthreads();
#pragma unroll
    for (int k = 0; k < STAGE_EPT; ++k) {
        if (d[k] >= 0) {
            int b = d[k] >> BSHIFT;
            int pos = atomicAdd(&base[rep][b], 1);
            if (pos < (b + 1) * BUCKET_CAP)  // statistically never false; memory-safety clamp
                staged[pos] = (unsigned)s[k] | ((unsigned)(d[k] & (BSIZE - 1)) << 17);
        }
    }
}

// ---------------- post-stage scan: counts from cursors -> boff ----------------
__global__ void bscan_kernel(const int* __restrict__ gcursor, int* __restrict__ boff) {
    __shared__ int s[1024];
    const int tid = threadIdx.x;
    int v = 0;
    if (tid < NBUCK) {
        v = gcursor[tid] - tid * BUCKET_CAP;   // bucket count
        if (v > BUCKET_CAP) v = BUCKET_CAP;
    }
    s[tid] = v;
    __syncthreads();
    for (int off = 1; off < 1024; off <<= 1) {
        int t = (tid >= off) ? s[tid - off] : 0;
        __syncthreads();
        s[tid] += t;
        __syncthreads();
    }
    if (tid < NBUCK) boff[tid] = s[tid] - v;  // exclusive
    if (tid == NBUCK - 1) boff[NBUCK] = s[tid];
}

// ---------------- per-bucket: deg/dinv/rowptr + fine CSR, all coalesced ----------------
__global__ void bucket_csr_kernel(const unsigned* __restrict__ staged,
                                  const int* __restrict__ boff,
                                  int* __restrict__ deg, float* __restrict__ dinv,
                                  int* __restrict__ rowptr, int* __restrict__ csrc, int n) {
    __shared__ int ldeg[BSIZE];
    __shared__ int lrp[BSIZE];
    __shared__ int lcnt[BSIZE];
    __shared__ unsigned lrec[BUCKET_CAP];
    __shared__ int lsrc[BUCKET_CAP];
    const int b = blockIdx.x;
    const int node0 = b * BSIZE;
    const int nn = min(BSIZE, n - node0);
    const int tid = threadIdx.x;  // 256
    if (tid < BSIZE) { ldeg[tid] = 0; lcnt[tid] = 0; }
    __syncthreads();
    const int ebase = boff[b];
    const int ecnt = min(boff[b + 1] - ebase, BUCKET_CAP);
    const int sbase = b * BUCKET_CAP;
    for (int i = tid; i < ecnt; i += 256) {
        unsigned r = staged[sbase + i];
        lrec[i] = r;
        atomicAdd(&ldeg[r >> 17], 1);
    }
    __syncthreads();
    int mydeg = (tid < BSIZE) ? ldeg[tid] : 0;
    if (tid < BSIZE) lrp[tid] = mydeg;
    __syncthreads();
    for (int off = 1; off < BSIZE; off <<= 1) {
        int v = 0;
        if (tid < BSIZE && tid >= off) v = lrp[tid - off];
        __syncthreads();
        if (tid < BSIZE) lrp[tid] += v;
        __syncthreads();
    }
    if (tid < BSIZE) {
        int ex = lrp[tid] - mydeg;  // exclusive
        lrp[tid] = ex;
        if (tid < nn) {
            deg[node0 + tid] = mydeg;
            dinv[node0 + tid] = rsqrtf((float)mydeg + 2.0f);
            rowptr[node0 + tid] = ebase + ex;
        }
    }
    __syncthreads();
    for (int i = tid; i < ecnt; i += 256) {
        unsigned r = lrec[i];
        int dl = (int)(r >> 17);
        int sv = (int)(r & 0x1FFFFu);
        int pos = lrp[dl] + atomicAdd(&lcnt[dl], 1);
        if (pos < BUCKET_CAP) lsrc[pos] = sv;
    }
    __syncthreads();
    for (int i = tid; i < ecnt; i += 256)
        csrc[ebase + i] = lsrc[i];
}

// ---------------- MFMA linear: HS = bf16x2((X@W)*dinv), chunked + (f,f+16) pairing ----------------
// Split GEMM: Ahi*Whi + Alo*Whi + Ahi*Wlo gives ~fp32 accuracy with bf16 MFMA.
// C/D layout (16x16x32_bf16): col=lane&15, row=(lane>>4)*4+reg.  A: [m=lane&15][k=(lane>>4)*8+j].
// HS chunk ch holds features [32ch,32ch+32); uint c of a row packs (feat 32ch+c, feat 32ch+16+c).
template <int FOUT>   // 64 or 32
__global__ void __launch_bounds__(256) linear_mfma_kernel(
    const float* __restrict__ X, const float* __restrict__ W,
    const float* __restrict__ dinv, unsigned* __restrict__ HS, int n) {
    constexpr int NT = FOUT / 16;            // n-tiles
    const int NTILES_M = n / 16;             // 6250 (n divisible by 16)
    const int lane = threadIdx.x & 63;
    const int gwave = blockIdx.x * 4 + (threadIdx.x >> 6);
    const int nwaves = gridDim.x * 4;
    const int m = lane & 15;
    const int q = lane >> 4;  // 0..3

    // W fragments in registers (hi+lo), loaded once per wave
    short8 Bhi[2][NT], Blo[2][NT];
#pragma unroll
    for (int ks = 0; ks < 2; ++ks)
#pragma unroll
        for (int nt = 0; nt < NT; ++nt) {
            short8 bh, bl;
#pragma unroll
            for (int j = 0; j < 8; ++j) {
                int k = ks * 32 + q * 8 + j;
                float wv = W[k * FOUT + nt * 16 + m];
                unsigned short h = f2bf(wv);
                bh[j] = (short)h;
                bl[j] = (short)f2bf(wv - bf2f(h));
            }
            Bhi[ks][nt] = bh;
            Blo[ks][nt] = bl;
        }

    for (int tile = gwave; tile < NTILES_M; tile += nwaves) {
        const int row0 = tile * 16;
        float4v C[NT];
#pragma unroll
        for (int nt = 0; nt < NT; ++nt) C[nt] = (float4v){0.f, 0.f, 0.f, 0.f};
#pragma unroll
        for (int ks = 0; ks < 2; ++ks) {
            const float* xp = X + (size_t)(row0 + m) * 64 + ks * 32 + q * 8;
            float4v x0 = *(const float4v*)xp;
            float4v x1 = *(const float4v*)(xp + 4);
            short8 Ahi, Alo;
#pragma unroll
            for (int j = 0; j < 4; ++j) {
                unsigned short h0 = f2bf(x0[j]);
                Ahi[j] = (short)h0;
                Alo[j] = (short)f2bf(x0[j] - bf2f(h0));
                unsigned short h1 = f2bf(x1[j]);
                Ahi[4 + j] = (short)h1;
                Alo[4 + j] = (short)f2bf(x1[j] - bf2f(h1));
            }
#pragma unroll
            for (int nt = 0; nt < NT; ++nt) {
                C[nt] = __builtin_amdgcn_mfma_f32_16x16x32_bf16(Ahi, Bhi[ks][nt], C[nt], 0, 0, 0);
                C[nt] = __builtin_amdgcn_mfma_f32_16x16x32_bf16(Alo, Bhi[ks][nt], C[nt], 0, 0, 0);
                C[nt] = __builtin_amdgcn_mfma_f32_16x16x32_bf16(Ahi, Blo[ks][nt], C[nt], 0, 0, 0);
            }
        }
        // epilogue: pair n-tile 2ch (cols 0-15) with 2ch+1 (cols 16-31) of chunk ch
#pragma unroll
        for (int ch = 0; ch < NT / 2; ++ch) {
#pragma unroll
            for (int reg = 0; reg < 4; ++reg) {
                int r = row0 + q * 4 + reg;
                float di = dinv[r];
                unsigned u = pack_bf16x2(C[2 * ch][reg] * di, C[2 * ch + 1][reg] * di);
                HS[(size_t)ch * n * 16 + (size_t)r * 16 + m] = u;
            }
        }
    }
}

// ---------------- fused gather over one 32-feature chunk ----------------
// G=16 lanes/node; uint l of a row = (feat base+l, feat base+16+l).
// Direct per-edge loads (group-uniform csrc scalar reads broadcast in HW);
// unroll-8 with two independent accumulator pairs for MLP.
template <bool RELU>
__global__ void gather_chunk_kernel(const int* __restrict__ rowptr, const int* __restrict__ deg,
                                    const int* __restrict__ csrc, const unsigned* __restrict__ HS,
                                    const float* __restrict__ dinv, const float* __restrict__ bias0,
                                    float* __restrict__ OUT, int out_stride, int out_off,
                                    int n) {
    constexpr int G = 16;
    constexpr int NPB = 256 / G;  // 16 nodes per block
    int node = blockIdx.x * NPB + (threadIdx.x / G);
    int l = threadIdx.x % G;
    if (node >= n) return;
    int start = rowptr[node];
    int cnt = deg[node];
    unsigned us = HS[(size_t)node * G + l];
    float a0 = 2.0f * bf_lo(us);
    float a1 = 2.0f * bf_hi(us);
    float b0 = 0.0f, b1 = 0.0f;
    int j = start, end = start + cnt;
    for (; j + 7 < end; j += 8) {
        int s0 = csrc[j],     s1 = csrc[j + 1], s2 = csrc[j + 2], s3 = csrc[j + 3];
        int s4 = csrc[j + 4], s5 = csrc[j + 5], s6 = csrc[j + 6], s7 = csrc[j + 7];
        unsigned u0 = HS[(size_t)s0 * G + l];
        unsigned u1 = HS[(size_t)s1 * G + l];
        unsigned u2 = HS[(size_t)s2 * G + l];
        unsigned u3 = HS[(size_t)s3 * G + l];
        unsigned u4 = HS[(size_t)s4 * G + l];
        unsigned u5 = HS[(size_t)s5 * G + l];
        unsigned u6 = HS[(size_t)s6 * G + l];
        unsigned u7 = HS[(size_t)s7 * G + l];
        a0 += bf_lo(u0) + bf_lo(u1) + bf_lo(u2) + bf_lo(u3);
        a1 += bf_hi(u0) + bf_hi(u1) + bf_hi(u2) + bf_hi(u3);
        b0 += bf_lo(u4) + bf_lo(u5) + bf_lo(u6) + bf_lo(u7);
        b1 += bf_hi(u4) + bf_hi(u5) + bf_hi(u6) + bf_hi(u7);
    }
    for (; j + 3 < end; j += 4) {
        int s0 = csrc[j], s1 = csrc[j + 1], s2 = csrc[j + 2], s3 = csrc[j + 3];
        unsigned u0 = HS[(size_t)s0 * G + l];
        unsigned u1 = HS[(size_t)s1 * G + l];
        unsigned u2 = HS[(size_t)s2 * G + l];
        unsigned u3 = HS[(size_t)s3 * G + l];
        a0 += bf_lo(u0) + bf_lo(u1);
        a1 += bf_hi(u0) + bf_hi(u1);
        b0 += bf_lo(u2) + bf_lo(u3);
        b1 += bf_hi(u2) + bf_hi(u3);
    }
    for (; j < end; ++j) {
        unsigned u = HS[(size_t)csrc[j] * G + l];
        a0 += bf_lo(u);
        a1 += bf_hi(u);
    }
    a0 += b0;
    a1 += b1;
    float dd = dinv[node];
    float o0 = a0 * dd + bias0[l];
    float o1 = a1 * dd + bias0[16 + l];
    if (RELU) { o0 = fmaxf(o0, 0.0f); o1 = fmaxf(o1, 0.0f); }
    OUT[(size_t)node * out_stride + out_off + l] = o0;
    OUT[(size_t)node * out_stride + out_off + 16 + l] = o1;
}

extern "C" void kernel_launch(void* const* d_in, const int* in_sizes, int n_in,
                              void* d_out, int out_size, void* d_ws, size_t ws_size,
                              hipStream_t stream) {
    const float* x  = (const float*)d_in[0];   // [N,64]
    const int*   ei = (const int*)d_in[1];     // [2,E] row-major: src then dst
    const float* W1 = (const float*)d_in[2];   // [64,64]
    const float* b1 = (const float*)d_in[3];   // [64]
    const float* W2 = (const float*)d_in[4];   // [64,32]
    const float* b2 = (const float*)d_in[5];   // [32]

    const int* srcp = ei;
    const int* dstp = ei + E_EDGES;

    // tuple return order: (out [N,32], feature_map [N,64]) concatenated flat
    float* out = (float*)d_out;                   // N*32
    float* fm  = (float*)d_out + N_NODES * 32;    // N*64 (also h1 input to layer 2)

    // workspace layout
    char* w = (char*)d_ws;
    int*      gcursor = (int*)w;       w += sizeof(int) * NBUCK;
    int*      boff    = (int*)w;       w += sizeof(int) * (NBUCK + 1);
    int*      deg     = (int*)w;       w += sizeof(int) * N_NODES;
    int*      rowptr  = (int*)w;       w += sizeof(int) * N_NODES;
    float*    dinv    = (float*)w;     w += sizeof(float) * N_NODES;
    int*      csrc    = (int*)w;       w += sizeof(int) * E_EDGES;
    unsigned* staged  = (unsigned*)w;  w += sizeof(unsigned) * (size_t)NBUCK * BUCKET_CAP;
    unsigned* HS1     = (unsigned*)w;  w += sizeof(unsigned) * (size_t)N_NODES * 32;  // 2 chunks x N x 16
    unsigned* HS2     = (unsigned*)w;  w += sizeof(unsigned) * (size_t)N_NODES * 16;  // 1 chunk

    // ---- graph preprocessing (shared by both layers) ----
    cursor_init_kernel<<<(NBUCK + 255) / 256, 256, 0, stream>>>(gcursor);
    stage_kernel<<<(E_EDGES + STAGE_CHUNK - 1) / STAGE_CHUNK, STAGE_TPB, 0, stream>>>(
        srcp, dstp, gcursor, staged, E_EDGES);
    bscan_kernel<<<1, 1024, 0, stream>>>(gcursor, boff);
    bucket_csr_kernel<<<NBUCK, 256, 0, stream>>>(staged, boff, deg, dinv, rowptr, csrc, N_NODES);

    // ---- layer 1: HS1 = bf16((x@W1)*dinv) via MFMA; fm = relu(gather) per chunk ----
    linear_mfma_kernel<64><<<512, 256, 0, stream>>>(x, W1, dinv, HS1, N_NODES);
    gather_chunk_kernel<true><<<(N_NODES + 15) / 16, 256, 0, stream>>>(
        rowptr, deg, csrc, HS1, dinv, b1, fm, 64, 0, N_NODES);
    gather_chunk_kernel<true><<<(N_NODES + 15) / 16, 256, 0, stream>>>(
        rowptr, deg, csrc, HS1 + (size_t)N_NODES * 16, dinv, b1 + 32, fm, 64, 32, N_NODES);

    // ---- layer 2: HS2 = bf16((fm@W2)*dinv) via MFMA; out = gather (one chunk) ----
    linear_mfma_kernel<32><<<512, 256, 0, stream>>>(fm, W2, dinv, HS2, N_NODES);
    gather_chunk_kernel<false><<<(N_NODES + 15) / 16, 256, 0, stream>>>(
        rowptr, deg, csrc, HS2, dinv, b2, out, 32, 0, N_NODES);
}

// Round 10
// 219.008 us; speedup vs baseline: 1.2011x; 1.0276x over previous
//
#include <hip/hip_runtime.h>

#define N_NODES 100000
#define E_EDGES 1600000

// bucketed CSR build
#define BSHIFT 7
#define BSIZE 128
#define NBUCK ((N_NODES + BSIZE - 1) / BSIZE)           // 782
#define STAGE_TPB 512
#define STAGE_EPT 8
#define STAGE_CHUNK (STAGE_TPB * STAGE_EPT)             // 4096
#define NREP 2                                           // LDS table replicas in stage
#define BUCKET_CAP 4096                                  // staged slots per bucket (mean 2046)

typedef __attribute__((ext_vector_type(8))) short short8;
typedef __attribute__((ext_vector_type(4))) float float4v;

// ---- bf16 helpers (RNE) ----
__device__ inline unsigned short f2bf(float f) {
    union { float f; unsigned u; } t; t.f = f;
    unsigned r = (t.u + 0x7fffu + ((t.u >> 16) & 1u)) >> 16;
    return (unsigned short)r;
}
__device__ inline float bf2f(unsigned short h) {
    union { unsigned u; float f; } t; t.u = ((unsigned)h) << 16; return t.f;
}
__device__ inline unsigned pack_bf16x2(float a, float b) {
    return (unsigned)f2bf(a) | ((unsigned)f2bf(b) << 16);
}
__device__ inline float bf_lo(unsigned u) { union { unsigned u; float f; } t; t.u = u << 16; return t.f; }
__device__ inline float bf_hi(unsigned u) { union { unsigned u; float f; } t; t.u = u & 0xffff0000u; return t.f; }

// ---------------- cursor init: gcursor[b] = b * BUCKET_CAP ----------------
__global__ void cursor_init_kernel(int* __restrict__ gcursor) {
    int b = blockIdx.x * blockDim.x + threadIdx.x;
    if (b < NBUCK) gcursor[b] = b * BUCKET_CAP;
}

// ---------------- stage edges into fixed-capacity bucket regions ----------------
// record = src | ((dst & 127) << 17); src < 2^17
// 512 thr / 391 blocks (~1.5 per CU); 2x replicated LDS tables (one per 256-thread slice).
__global__ void __launch_bounds__(STAGE_TPB) stage_kernel(
    const int* __restrict__ src, const int* __restrict__ dst,
    int* __restrict__ gcursor, unsigned* __restrict__ staged, int E) {
    __shared__ int hist[NREP][NBUCK];
    __shared__ int base[NREP][NBUCK];   // doubles as the per-replica write cursor
    const int tid = threadIdx.x;
    const int rep = (tid >> 8) & (NREP - 1);
    const int e0 = blockIdx.x * STAGE_CHUNK;
    for (int i = tid; i < NREP * NBUCK; i += STAGE_TPB) ((int*)hist)[i] = 0;
    __syncthreads();
    int d[STAGE_EPT], s[STAGE_EPT];
#pragma unroll
    for (int k = 0; k < STAGE_EPT; ++k) {
        int e = e0 + k * STAGE_TPB + tid;
        if (e < E) {
            d[k] = dst[e];
            s[k] = src[e];
            atomicAdd(&hist[rep][d[k] >> BSHIFT], 1);
        } else {
            d[k] = -1;
        }
    }
    __syncthreads();
    for (int i = tid; i < NBUCK; i += STAGE_TPB) {
        int h0 = hist[0][i], h1 = hist[1][i];
        int t = h0 + h1;
        if (t > 0) {
            int g = atomicAdd(&gcursor[i], t);
            base[0][i] = g;
            base[1][i] = g + h0;
        }
    }
    __syncthreads();
#pragma unroll
    for (int k = 0; k < STAGE_EPT; ++k) {
        if (d[k] >= 0) {
            int b = d[k] >> BSHIFT;
            int pos = atomicAdd(&base[rep][b], 1);
            if (pos < (b + 1) * BUCKET_CAP)  // statistically never false; memory-safety clamp
                staged[pos] = (unsigned)s[k] | ((unsigned)(d[k] & (BSIZE - 1)) << 17);
        }
    }
}

// ---------------- post-stage scan: counts from cursors -> boff ----------------
__global__ void bscan_kernel(const int* __restrict__ gcursor, int* __restrict__ boff) {
    __shared__ int s[1024];
    const int tid = threadIdx.x;
    int v = 0;
    if (tid < NBUCK) {
        v = gcursor[tid] - tid * BUCKET_CAP;   // bucket count
        if (v > BUCKET_CAP) v = BUCKET_CAP;
    }
    s[tid] = v;
    __syncthreads();
    for (int off = 1; off < 1024; off <<= 1) {
        int t = (tid >= off) ? s[tid - off] : 0;
        __syncthreads();
        s[tid] += t;
        __syncthreads();
    }
    if (tid < NBUCK) boff[tid] = s[tid] - v;  // exclusive
    if (tid == NBUCK - 1) boff[NBUCK] = s[tid];
}

// ---------------- per-bucket: nodeinfo/dinv + fine CSR, all coalesced ----------------
// nodeinfo[node] = {edge_start, deg}
__global__ void bucket_csr_kernel(const unsigned* __restrict__ staged,
                                  const int* __restrict__ boff,
                                  int2* __restrict__ nodeinfo, float* __restrict__ dinv,
                                  int* __restrict__ csrc, int n) {
    __shared__ int ldeg[BSIZE];
    __shared__ int lrp[BSIZE];
    __shared__ int lcnt[BSIZE];
    __shared__ unsigned lrec[BUCKET_CAP];
    __shared__ int lsrc[BUCKET_CAP];
    const int b = blockIdx.x;
    const int node0 = b * BSIZE;
    const int nn = min(BSIZE, n - node0);
    const int tid = threadIdx.x;  // 256
    if (tid < BSIZE) { ldeg[tid] = 0; lcnt[tid] = 0; }
    __syncthreads();
    const int ebase = boff[b];
    const int ecnt = min(boff[b + 1] - ebase, BUCKET_CAP);
    const int sbase = b * BUCKET_CAP;
    for (int i = tid; i < ecnt; i += 256) {
        unsigned r = staged[sbase + i];
        lrec[i] = r;
        atomicAdd(&ldeg[r >> 17], 1);
    }
    __syncthreads();
    int mydeg = (tid < BSIZE) ? ldeg[tid] : 0;
    if (tid < BSIZE) lrp[tid] = mydeg;
    __syncthreads();
    for (int off = 1; off < BSIZE; off <<= 1) {
        int v = 0;
        if (tid < BSIZE && tid >= off) v = lrp[tid - off];
        __syncthreads();
        if (tid < BSIZE) lrp[tid] += v;
        __syncthreads();
    }
    if (tid < BSIZE) {
        int ex = lrp[tid] - mydeg;  // exclusive
        lrp[tid] = ex;
        if (tid < nn) {
            nodeinfo[node0 + tid] = make_int2(ebase + ex, mydeg);
            dinv[node0 + tid] = rsqrtf((float)mydeg + 2.0f);
        }
    }
    __syncthreads();
    for (int i = tid; i < ecnt; i += 256) {
        unsigned r = lrec[i];
        int dl = (int)(r >> 17);
        int sv = (int)(r & 0x1FFFFu);
        int pos = lrp[dl] + atomicAdd(&lcnt[dl], 1);
        if (pos < BUCKET_CAP) lsrc[pos] = sv;
    }
    __syncthreads();
    for (int i = tid; i < ecnt; i += 256)
        csrc[ebase + i] = lsrc[i];
}

// ---------------- MFMA linear: HS = bf16x2((X@W)*dinv), chunked + (f,f+16) pairing ----------------
// Split GEMM: Ahi*Whi + Alo*Whi + Ahi*Wlo gives ~fp32 accuracy with bf16 MFMA.
// C/D layout (16x16x32_bf16): col=lane&15, row=(lane>>4)*4+reg.  A: [m=lane&15][k=(lane>>4)*8+j].
// HS chunk ch holds features [32ch,32ch+32); uint c of a row packs (feat 32ch+c, feat 32ch+16+c).
template <int FOUT>   // 64 or 32
__global__ void __launch_bounds__(256) linear_mfma_kernel(
    const float* __restrict__ X, const float* __restrict__ W,
    const float* __restrict__ dinv, unsigned* __restrict__ HS, int n) {
    constexpr int NT = FOUT / 16;            // n-tiles
    const int NTILES_M = n / 16;             // 6250 (n divisible by 16)
    const int lane = threadIdx.x & 63;
    const int gwave = blockIdx.x * 4 + (threadIdx.x >> 6);
    const int nwaves = gridDim.x * 4;
    const int m = lane & 15;
    const int q = lane >> 4;  // 0..3

    // W fragments in registers (hi+lo), loaded once per wave
    short8 Bhi[2][NT], Blo[2][NT];
#pragma unroll
    for (int ks = 0; ks < 2; ++ks)
#pragma unroll
        for (int nt = 0; nt < NT; ++nt) {
            short8 bh, bl;
#pragma unroll
            for (int j = 0; j < 8; ++j) {
                int k = ks * 32 + q * 8 + j;
                float wv = W[k * FOUT + nt * 16 + m];
                unsigned short h = f2bf(wv);
                bh[j] = (short)h;
                bl[j] = (short)f2bf(wv - bf2f(h));
            }
            Bhi[ks][nt] = bh;
            Blo[ks][nt] = bl;
        }

    for (int tile = gwave; tile < NTILES_M; tile += nwaves) {
        const int row0 = tile * 16;
        float4v C[NT];
#pragma unroll
        for (int nt = 0; nt < NT; ++nt) C[nt] = (float4v){0.f, 0.f, 0.f, 0.f};
#pragma unroll
        for (int ks = 0; ks < 2; ++ks) {
            const float* xp = X + (size_t)(row0 + m) * 64 + ks * 32 + q * 8;
            float4v x0 = *(const float4v*)xp;
            float4v x1 = *(const float4v*)(xp + 4);
            short8 Ahi, Alo;
#pragma unroll
            for (int j = 0; j < 4; ++j) {
                unsigned short h0 = f2bf(x0[j]);
                Ahi[j] = (short)h0;
                Alo[j] = (short)f2bf(x0[j] - bf2f(h0));
                unsigned short h1 = f2bf(x1[j]);
                Ahi[4 + j] = (short)h1;
                Alo[4 + j] = (short)f2bf(x1[j] - bf2f(h1));
            }
#pragma unroll
            for (int nt = 0; nt < NT; ++nt) {
                C[nt] = __builtin_amdgcn_mfma_f32_16x16x32_bf16(Ahi, Bhi[ks][nt], C[nt], 0, 0, 0);
                C[nt] = __builtin_amdgcn_mfma_f32_16x16x32_bf16(Alo, Bhi[ks][nt], C[nt], 0, 0, 0);
                C[nt] = __builtin_amdgcn_mfma_f32_16x16x32_bf16(Ahi, Blo[ks][nt], C[nt], 0, 0, 0);
            }
        }
        // epilogue: pair n-tile 2ch (cols 0-15) with 2ch+1 (cols 16-31) of chunk ch
#pragma unroll
        for (int ch = 0; ch < NT / 2; ++ch) {
#pragma unroll
            for (int reg = 0; reg < 4; ++reg) {
                int r = row0 + q * 4 + reg;
                float di = dinv[r];
                unsigned u = pack_bf16x2(C[2 * ch][reg] * di, C[2 * ch + 1][reg] * di);
                HS[(size_t)ch * n * 16 + (size_t)r * 16 + m] = u;
            }
        }
    }
}

// ---------------- fused gather, NCHUNK 32-feature chunks in one dispatch ----------------
// G=16 lanes/node; uint l of a row = (feat base+l, feat base+16+l).
// chunk = blockIdx.x & (NCHUNK-1): consecutive blocks share the node range -> csrc L2 reuse.
// Direct per-edge loads, unroll-8, two accumulator pairs for MLP.
template <int NCHUNK, bool RELU>
__global__ void gather_chunk_kernel(const int2* __restrict__ nodeinfo,
                                    const int* __restrict__ csrc, const unsigned* __restrict__ HS0,
                                    const float* __restrict__ dinv, const float* __restrict__ bias,
                                    float* __restrict__ OUT, int n) {
    constexpr int G = 16;
    constexpr int NPB = 256 / G;  // 16 nodes per block
    const int chunk = blockIdx.x & (NCHUNK - 1);
    int node = (blockIdx.x / NCHUNK) * NPB + (threadIdx.x / G);
    int l = threadIdx.x % G;
    if (node >= n) return;
    const unsigned* __restrict__ HS = HS0 + (size_t)chunk * n * G;
    const float* __restrict__ bias0 = bias + 32 * chunk;
    const int out_stride = 32 * NCHUNK;
    const int out_off = 32 * chunk;
    int2 ni = nodeinfo[node];
    int start = ni.x, cnt = ni.y;
    unsigned us = HS[(size_t)node * G + l];
    float a0 = 2.0f * bf_lo(us);
    float a1 = 2.0f * bf_hi(us);
    float b0 = 0.0f, b1 = 0.0f;
    int j = start, end = start + cnt;
    for (; j + 7 < end; j += 8) {
        int s0 = csrc[j],     s1 = csrc[j + 1], s2 = csrc[j + 2], s3 = csrc[j + 3];
        int s4 = csrc[j + 4], s5 = csrc[j + 5], s6 = csrc[j + 6], s7 = csrc[j + 7];
        unsigned u0 = HS[(size_t)s0 * G + l];
        unsigned u1 = HS[(size_t)s1 * G + l];
        unsigned u2 = HS[(size_t)s2 * G + l];
        unsigned u3 = HS[(size_t)s3 * G + l];
        unsigned u4 = HS[(size_t)s4 * G + l];
        unsigned u5 = HS[(size_t)s5 * G + l];
        unsigned u6 = HS[(size_t)s6 * G + l];
        unsigned u7 = HS[(size_t)s7 * G + l];
        a0 += bf_lo(u0) + bf_lo(u1) + bf_lo(u2) + bf_lo(u3);
        a1 += bf_hi(u0) + bf_hi(u1) + bf_hi(u2) + bf_hi(u3);
        b0 += bf_lo(u4) + bf_lo(u5) + bf_lo(u6) + bf_lo(u7);
        b1 += bf_hi(u4) + bf_hi(u5) + bf_hi(u6) + bf_hi(u7);
    }
    for (; j + 3 < end; j += 4) {
        int s0 = csrc[j], s1 = csrc[j + 1], s2 = csrc[j + 2], s3 = csrc[j + 3];
        unsigned u0 = HS[(size_t)s0 * G + l];
        unsigned u1 = HS[(size_t)s1 * G + l];
        unsigned u2 = HS[(size_t)s2 * G + l];
        unsigned u3 = HS[(size_t)s3 * G + l];
        a0 += bf_lo(u0) + bf_lo(u1);
        a1 += bf_hi(u0) + bf_hi(u1);
        b0 += bf_lo(u2) + bf_lo(u3);
        b1 += bf_hi(u2) + bf_hi(u3);
    }
    for (; j < end; ++j) {
        unsigned u = HS[(size_t)csrc[j] * G + l];
        a0 += bf_lo(u);
        a1 += bf_hi(u);
    }
    a0 += b0;
    a1 += b1;
    float dd = dinv[node];
    float o0 = a0 * dd + bias0[l];
    float o1 = a1 * dd + bias0[16 + l];
    if (RELU) { o0 = fmaxf(o0, 0.0f); o1 = fmaxf(o1, 0.0f); }
    OUT[(size_t)node * out_stride + out_off + l] = o0;
    OUT[(size_t)node * out_stride + out_off + 16 + l] = o1;
}

extern "C" void kernel_launch(void* const* d_in, const int* in_sizes, int n_in,
                              void* d_out, int out_size, void* d_ws, size_t ws_size,
                              hipStream_t stream) {
    const float* x  = (const float*)d_in[0];   // [N,64]
    const int*   ei = (const int*)d_in[1];     // [2,E] row-major: src then dst
    const float* W1 = (const float*)d_in[2];   // [64,64]
    const float* b1 = (const float*)d_in[3];   // [64]
    const float* W2 = (const float*)d_in[4];   // [64,32]
    const float* b2 = (const float*)d_in[5];   // [32]

    const int* srcp = ei;
    const int* dstp = ei + E_EDGES;

    // tuple return order: (out [N,32], feature_map [N,64]) concatenated flat
    float* out = (float*)d_out;                   // N*32
    float* fm  = (float*)d_out + N_NODES * 32;    // N*64 (also h1 input to layer 2)

    // workspace layout
    char* w = (char*)d_ws;
    int*      gcursor  = (int*)w;       w += sizeof(int) * NBUCK;
    int*      boff     = (int*)w;       w += sizeof(int) * (NBUCK + 1);
    int2*     nodeinfo = (int2*)w;      w += sizeof(int2) * N_NODES;
    float*    dinv     = (float*)w;     w += sizeof(float) * N_NODES;
    int*      csrc     = (int*)w;       w += sizeof(int) * E_EDGES;
    unsigned* staged   = (unsigned*)w;  w += sizeof(unsigned) * (size_t)NBUCK * BUCKET_CAP;
    unsigned* HS1      = (unsigned*)w;  w += sizeof(unsigned) * (size_t)N_NODES * 32;  // 2 chunks x N x 16
    unsigned* HS2      = (unsigned*)w;  w += sizeof(unsigned) * (size_t)N_NODES * 16;  // 1 chunk

    // ---- graph preprocessing (shared by both layers) ----
    cursor_init_kernel<<<(NBUCK + 255) / 256, 256, 0, stream>>>(gcursor);
    stage_kernel<<<(E_EDGES + STAGE_CHUNK - 1) / STAGE_CHUNK, STAGE_TPB, 0, stream>>>(
        srcp, dstp, gcursor, staged, E_EDGES);
    bscan_kernel<<<1, 1024, 0, stream>>>(gcursor, boff);
    bucket_csr_kernel<<<NBUCK, 256, 0, stream>>>(staged, boff, nodeinfo, dinv, csrc, N_NODES);

    // ---- layer 1: HS1 = bf16((x@W1)*dinv) via MFMA; fm = relu(gather), both chunks fused ----
    linear_mfma_kernel<64><<<512, 256, 0, stream>>>(x, W1, dinv, HS1, N_NODES);
    gather_chunk_kernel<2, true><<<2 * ((N_NODES + 15) / 16), 256, 0, stream>>>(
        nodeinfo, csrc, HS1, dinv, b1, fm, N_NODES);

    // ---- layer 2: HS2 = bf16((fm@W2)*dinv) via MFMA; out = gather (one chunk) ----
    linear_mfma_kernel<32><<<512, 256, 0, stream>>>(fm, W2, dinv, HS2, N_NODES);
    gather_chunk_kernel<1, false><<<(N_NODES + 15) / 16, 256, 0, stream>>>(
        nodeinfo, csrc, HS2, dinv, b2, out, N_NODES);
}